// Round 10
// baseline (328.598 us; speedup 1.0000x reference)
//
#include <hip/hip_runtime.h>
#include <math.h>

#define BB 32
#define CC 256
#define OO 256
#define HW 56
#define SP (HW*HW)      // 3136
#define KK 4
#define HID 129
#define TEMP 34.0f
#define PROW 58                       // padded rows/cols (1-halo each side)
#define PLANE (PROW*PROW*32)          // u16 per (b,cb) plane = 107648

typedef unsigned short u16;
typedef unsigned int uint32;
typedef __attribute__((ext_vector_type(8))) short bf16x8;
typedef __attribute__((ext_vector_type(4))) float f32x4;

__device__ __forceinline__ u16 f2bf(float f) {
    union { float f; uint32 u; } v; v.f = f;
    uint32 r = v.u + 0x7FFF + ((v.u >> 16) & 1);
    return (u16)(r >> 16);
}

// ---------------- Stage 1: fused transpose->bf16 (zero-padded) + mix pooling ----
// x_t[b][cb][(r+1)*58 + (col+1)][32c] bf16, halo slots zeroed -> conv taps are
// plain loads with no masking anywhere.
__global__ __launch_bounds__(256) void trans_pool(const float* __restrict__ x,
                                                  u16* __restrict__ xt,
                                                  float* __restrict__ pooled) {
    const int cb = blockIdx.x, b = blockIdx.y;
    const int tid = threadIdx.x;
    const int lane = tid & 63, wave = tid >> 6;
    const float* xp = x + ((size_t)b * CC + cb * 32) * SP;
    u16* xtb = xt + (size_t)(b * 8 + cb) * PLANE;

    // zero the 228 halo slots (top/bottom rows, left/right cols)
    if (tid < 228) {
        int slot;
        if (tid < 58)       slot = tid;                       // row 0
        else if (tid < 116) slot = 57 * 58 + (tid - 58);      // row 57
        else if (tid < 172) slot = (tid - 116 + 1) * 58;      // col 0, rows 1..56
        else                slot = (tid - 172 + 1) * 58 + 57; // col 57, rows 1..56
        bf16x8 z = {};
        #pragma unroll
        for (int j = 0; j < 4; ++j)
            *(bf16x8*)&xtb[(size_t)slot * 32 + j * 8] = z;
    }

    float psum[32], pmax[32];
    #pragma unroll
    for (int c = 0; c < 32; ++c) { psum[c] = 0.f; pmax[c] = -INFINITY; }

    for (int p0 = 0; p0 < SP; p0 += 256) {
        const int p = p0 + tid;
        const bool v = p < SP;
        const int pc = v ? p : (SP - 1);
        u16 ob[32];
        #pragma unroll
        for (int c = 0; c < 32; ++c) {
            const float vv = xp[(size_t)c * SP + pc];
            if (v) { psum[c] += vv; pmax[c] = fmaxf(pmax[c], vv); }
            ob[c] = f2bf(vv);
        }
        if (v) {
            const int slot = (p / 56 + 1) * 58 + (p % 56 + 1);
            #pragma unroll
            for (int j = 0; j < 4; ++j)
                *(bf16x8*)&xtb[(size_t)slot * 32 + j * 8] = *(bf16x8*)&ob[j * 8];
        }
    }
    #pragma unroll
    for (int c = 0; c < 32; ++c) {
        #pragma unroll
        for (int off = 32; off >= 1; off >>= 1) {
            psum[c] += __shfl_xor(psum[c], off, 64);
            pmax[c] = fmaxf(pmax[c], __shfl_xor(pmax[c], off, 64));
        }
    }
    __shared__ float ssum[4][32];
    __shared__ float smax[4][32];
    if (lane == 0) {
        #pragma unroll
        for (int c = 0; c < 32; ++c) { ssum[wave][c] = psum[c]; smax[wave][c] = pmax[c]; }
    }
    __syncthreads();
    if (tid < 32) {
        const float s = ssum[0][tid] + ssum[1][tid] + ssum[2][tid] + ssum[3][tid];
        const float m = fmaxf(fmaxf(smax[0][tid], smax[1][tid]),
                              fmaxf(smax[2][tid], smax[3][tid]));
        pooled[b * (2 * CC) + cb * 32 + tid]      = s / (float)SP;
        pooled[b * (2 * CC) + CC + cb * 32 + tid] = m;
    }
}

// ---------------- Stage 2: attention MLP + softmax + agg bias ----------------
__global__ __launch_bounds__(256) void attn_kernel(const float* __restrict__ pooled,
                                                   const float* __restrict__ w1,
                                                   const float* __restrict__ w2,
                                                   const float* __restrict__ b2,
                                                   const float* __restrict__ bias_k,
                                                   float* __restrict__ attn,
                                                   float* __restrict__ agg_b) {
    const int b = blockIdx.x;
    const int tid = threadIdx.x;
    __shared__ float p[2 * CC];
    __shared__ float h[HID];
    __shared__ float a[KK];
    for (int i = tid; i < 2 * CC; i += 256) p[i] = pooled[b * 2 * CC + i];
    __syncthreads();
    if (tid < HID) {
        float s = 0.f;
        const float* w1r = w1 + (size_t)tid * (2 * CC);
        for (int c = 0; c < 2 * CC; ++c) s = fmaf(p[c], w1r[c], s);
        h[tid] = fmaxf(s, 0.f);
    }
    __syncthreads();
    if (tid == 0) {
        float lg[KK];
        float m = -INFINITY;
        for (int k = 0; k < KK; ++k) {
            float s = b2[k];
            for (int i = 0; i < HID; ++i) s = fmaf(h[i], w2[k * HID + i], s);
            lg[k] = s / TEMP;
            m = fmaxf(m, lg[k]);
        }
        float den = 0.f;
        for (int k = 0; k < KK; ++k) { lg[k] = expf(lg[k] - m); den += lg[k]; }
        for (int k = 0; k < KK; ++k) { a[k] = lg[k] / den; attn[b * KK + k] = a[k]; }
    }
    __syncthreads();
    if (tid < OO) {
        float s = 0.f;
        #pragma unroll
        for (int k = 0; k < KK; ++k) s = fmaf(a[k], bias_k[k * OO + tid], s);
        agg_b[b * OO + tid] = s;
    }
}

// ---------------- Stage 2b: aggregate weights -> bf16, layout wT[b][uv][o][c] ----
__global__ __launch_bounds__(256) void agg_kernel(const float* __restrict__ weight,
                                                  const float* __restrict__ attn,
                                                  u16* __restrict__ wT) {
    const int o = blockIdx.x;
    const int c = threadIdx.x;
    __shared__ float at[BB * KK];
    if (threadIdx.x < BB * KK) at[threadIdx.x] = attn[threadIdx.x];
    __syncthreads();
    float w[KK][9];
    #pragma unroll
    for (int k = 0; k < KK; ++k)
        #pragma unroll
        for (int uv = 0; uv < 9; ++uv)
            w[k][uv] = weight[(size_t)((k * OO + o) * CC + c) * 9 + uv];
    for (int b = 0; b < BB; ++b) {
        const float a0 = at[b*KK+0], a1 = at[b*KK+1], a2 = at[b*KK+2], a3 = at[b*KK+3];
        #pragma unroll
        for (int uv = 0; uv < 9; ++uv) {
            float s = a0 * w[0][uv] + a1 * w[1][uv] + a2 * w[2][uv] + a3 * w[3][uv];
            wT[(size_t)((b * 9 + uv) * OO + o) * CC + c] = f2bf(s);
        }
    }
}

// ---------------- Stage 3: MFMA implicit-GEMM conv — BARRIER-FREE ----------------
// 1-D grid of 896 blocks, XCD-pinned: b = (id&7) + 8*((id>>3)/28) keeps a
// sample's tiles on one XCD (wT[b]+x_t[b] ~ 2.9 MB < 4 MB L2).
// No LDS, no __syncthreads: A (wT) and B (zero-padded x_t) fragments are read
// directly from L2. Each wave is an independent 99-load/252-MFMA stream per
// 32-channel chunk; with no barrier fences the compiler hoists loads freely
// and the 2 waves/SIMD cover each other's L2 latency (the per-chunk barrier
// drain was the structural stall R7-R9's manual pipelining couldn't touch).
__global__ __launch_bounds__(256, 2) void conv_mfma(const u16* __restrict__ xt,
                                                    const u16* __restrict__ wT,
                                                    const float* __restrict__ agg_b,
                                                    float* __restrict__ out) {
    const int id   = blockIdx.x;
    const int g    = id >> 3;
    const int b    = (id & 7) + 8 * (g / 28);
    const int tile = g % 28;
    const int px   = tile % 14, oy = tile / 14;
    const int tid  = threadIdx.x;
    const int lane = tid & 63, wave = tid >> 6;
    const int wm = wave & 1, wn = wave >> 1;
    const int l15 = lane & 15, kg = lane >> 4;
    const int p0 = px * 224;

    // B base pointers per n-fragment (padded-plane slot of output pixel n)
    const u16* xq[7];
    #pragma unroll
    for (int nf = 0; nf < 7; ++nf) {
        const int n   = wn * 112 + nf * 16 + l15;
        const int R   = px * 4 + n / 56;
        const int col = n % 56;
        const int slot = (R + 1) * PROW + (col + 1);
        xq[nf] = xt + (size_t)(b * 8) * PLANE + (size_t)slot * 32 + kg * 8;
    }

    // A-operand: wT[b][uv][o][c], o = oy*128 + wm*64 + mf*16 + l15, c = c0 + kg*8
    const u16* wTb = wT + (size_t)b * 9 * OO * CC
                        + (size_t)(oy * 128 + wm * 64 + l15) * CC + kg * 8;

    f32x4 acc[4][7];
    #pragma unroll
    for (int mf = 0; mf < 4; ++mf)
        #pragma unroll
        for (int nf = 0; nf < 7; ++nf)
            acc[mf][nf] = (f32x4)0.f;

    for (int cb = 0; cb < 8; ++cb) {
        const int c0 = cb * 32;
        const size_t cplane = (size_t)cb * PLANE;
        #pragma unroll
        for (int uv = 0; uv < 9; ++uv) {
            const int du = uv / 3 - 1, dv = uv % 3 - 1;
            const int toff = (du * PROW + dv) * 32;   // u16 units, |.|<=1888
            bf16x8 av[4];
            #pragma unroll
            for (int mf = 0; mf < 4; ++mf)
                av[mf] = *(const bf16x8*)(wTb + (size_t)uv * OO * CC + mf * 16 * CC + c0);
            #pragma unroll
            for (int nf = 0; nf < 7; ++nf) {
                const bf16x8 bv = *(const bf16x8*)(xq[nf] + cplane + toff);
                #pragma unroll
                for (int mf = 0; mf < 4; ++mf)
                    acc[mf][nf] = __builtin_amdgcn_mfma_f32_16x16x32_bf16(av[mf], bv, acc[mf][nf], 0, 0, 0);
            }
        }
    }

    // epilogue: D row = kg*4 + r (-> o), col = l15 (-> p)
    const int obase = oy * 128 + wm * 64;
    float* outb = out + (size_t)b * OO * SP;
    #pragma unroll
    for (int mf = 0; mf < 4; ++mf) {
        #pragma unroll
        for (int r = 0; r < 4; ++r) {
            const int o = obase + mf * 16 + kg * 4 + r;
            const float bias = agg_b[b * OO + o];
            #pragma unroll
            for (int nf = 0; nf < 7; ++nf) {
                const int p = p0 + wn * 112 + nf * 16 + l15;
                outb[(size_t)o * SP + p] = acc[mf][nf][r] + bias;
            }
        }
    }
}

extern "C" void kernel_launch(void* const* d_in, const int* in_sizes, int n_in,
                              void* d_out, int out_size, void* d_ws, size_t ws_size,
                              hipStream_t stream) {
    const float* x      = (const float*)d_in[0];
    const float* weight = (const float*)d_in[1];
    const float* bias_k = (const float*)d_in[2];
    const float* w1     = (const float*)d_in[3];
    const float* w2     = (const float*)d_in[4];
    const float* b2     = (const float*)d_in[5];
    float* out = (float*)d_out;

    // workspace: x_t padded bf16 (55.1 MB) | wT bf16 (37.75 MB) | fp32 scratch
    u16* x_t = (u16*)d_ws;
    u16* wT  = x_t + (size_t)BB * 8 * PLANE;
    float* ws_f   = (float*)(wT + (size_t)BB * 9 * OO * CC);
    float* pooled = ws_f;
    float* attn   = ws_f + BB * 2 * CC;
    float* agg_b  = attn + BB * KK;

    trans_pool<<<dim3(8, BB), 256, 0, stream>>>(x, x_t, pooled);
    attn_kernel<<<BB, 256, 0, stream>>>(pooled, w1, w2, b2, bias_k, attn, agg_b);
    agg_kernel<<<OO, 256, 0, stream>>>(weight, attn, wT);
    conv_mfma<<<896, 256, 0, stream>>>(x_t, wT, agg_b, out);
}

// Round 11
// 233.210 us; speedup vs baseline: 1.4090x; 1.4090x over previous
//
#include <hip/hip_runtime.h>
#include <math.h>

#define BB 32
#define CC 256
#define OO 256
#define HW 56
#define SP (HW*HW)      // 3136
#define KK 4
#define HID 129
#define TEMP 34.0f
#define PROW 58                       // padded rows/cols (1-halo each side)
#define PLANE (PROW*PROW*32)          // u16 per (b,cb) plane = 107648
#define PLANEB (PROW*PROW*64)         // bytes per (b,cb) plane = 215296
#define NSLOT 348                     // 6*58 slots per staged window
#define QSTRIDE (NSLOT*16)            // 5568 B per q-plane in LDS
#define BUFB (4*QSTRIDE)              // 22272 B per LDS buffer

typedef unsigned short u16;
typedef unsigned int uint32;
typedef __attribute__((ext_vector_type(8))) short bf16x8;
typedef __attribute__((ext_vector_type(4))) float f32x4;

__device__ __forceinline__ u16 f2bf(float f) {
    union { float f; uint32 u; } v; v.f = f;
    uint32 r = v.u + 0x7FFF + ((v.u >> 16) & 1);
    return (u16)(r >> 16);
}

__device__ __forceinline__ void gload16(const void* g, void* l) {
    __builtin_amdgcn_global_load_lds(
        (const __attribute__((address_space(1))) unsigned int*)g,
        (__attribute__((address_space(3))) unsigned int*)l, 16, 0, 0);
}

// ---------------- Stage 1: fused transpose->bf16 (zero-padded) + mix pooling ----
// x_t[b][cb][(r+1)*58 + (col+1)][32c] bf16, halo slots zeroed.
__global__ __launch_bounds__(256) void trans_pool(const float* __restrict__ x,
                                                  u16* __restrict__ xt,
                                                  float* __restrict__ pooled) {
    const int cb = blockIdx.x, b = blockIdx.y;
    const int tid = threadIdx.x;
    const int lane = tid & 63, wave = tid >> 6;
    const float* xp = x + ((size_t)b * CC + cb * 32) * SP;
    u16* xtb = xt + (size_t)(b * 8 + cb) * PLANE;

    // zero the 228 halo slots
    if (tid < 228) {
        int slot;
        if (tid < 58)       slot = tid;                       // row 0
        else if (tid < 116) slot = 57 * 58 + (tid - 58);      // row 57
        else if (tid < 172) slot = (tid - 116 + 1) * 58;      // col 0, rows 1..56
        else                slot = (tid - 172 + 1) * 58 + 57; // col 57, rows 1..56
        bf16x8 z = {};
        #pragma unroll
        for (int j = 0; j < 4; ++j)
            *(bf16x8*)&xtb[(size_t)slot * 32 + j * 8] = z;
    }

    float psum[32], pmax[32];
    #pragma unroll
    for (int c = 0; c < 32; ++c) { psum[c] = 0.f; pmax[c] = -INFINITY; }

    for (int p0 = 0; p0 < SP; p0 += 256) {
        const int p = p0 + tid;
        const bool v = p < SP;
        const int pc = v ? p : (SP - 1);
        u16 ob[32];
        #pragma unroll
        for (int c = 0; c < 32; ++c) {
            const float vv = xp[(size_t)c * SP + pc];
            if (v) { psum[c] += vv; pmax[c] = fmaxf(pmax[c], vv); }
            ob[c] = f2bf(vv);
        }
        if (v) {
            const int slot = (p / 56 + 1) * 58 + (p % 56 + 1);
            #pragma unroll
            for (int j = 0; j < 4; ++j)
                *(bf16x8*)&xtb[(size_t)slot * 32 + j * 8] = *(bf16x8*)&ob[j * 8];
        }
    }
    #pragma unroll
    for (int c = 0; c < 32; ++c) {
        #pragma unroll
        for (int off = 32; off >= 1; off >>= 1) {
            psum[c] += __shfl_xor(psum[c], off, 64);
            pmax[c] = fmaxf(pmax[c], __shfl_xor(pmax[c], off, 64));
        }
    }
    __shared__ float ssum[4][32];
    __shared__ float smax[4][32];
    if (lane == 0) {
        #pragma unroll
        for (int c = 0; c < 32; ++c) { ssum[wave][c] = psum[c]; smax[wave][c] = pmax[c]; }
    }
    __syncthreads();
    if (tid < 32) {
        const float s = ssum[0][tid] + ssum[1][tid] + ssum[2][tid] + ssum[3][tid];
        const float m = fmaxf(fmaxf(smax[0][tid], smax[1][tid]),
                              fmaxf(smax[2][tid], smax[3][tid]));
        pooled[b * (2 * CC) + cb * 32 + tid]      = s / (float)SP;
        pooled[b * (2 * CC) + CC + cb * 32 + tid] = m;
    }
}

// ---------------- Stage 2: attention MLP + softmax + agg bias ----------------
__global__ __launch_bounds__(256) void attn_kernel(const float* __restrict__ pooled,
                                                   const float* __restrict__ w1,
                                                   const float* __restrict__ w2,
                                                   const float* __restrict__ b2,
                                                   const float* __restrict__ bias_k,
                                                   float* __restrict__ attn,
                                                   float* __restrict__ agg_b) {
    const int b = blockIdx.x;
    const int tid = threadIdx.x;
    __shared__ float p[2 * CC];
    __shared__ float h[HID];
    __shared__ float a[KK];
    for (int i = tid; i < 2 * CC; i += 256) p[i] = pooled[b * 2 * CC + i];
    __syncthreads();
    if (tid < HID) {
        float s = 0.f;
        const float* w1r = w1 + (size_t)tid * (2 * CC);
        for (int c = 0; c < 2 * CC; ++c) s = fmaf(p[c], w1r[c], s);
        h[tid] = fmaxf(s, 0.f);
    }
    __syncthreads();
    if (tid == 0) {
        float lg[KK];
        float m = -INFINITY;
        for (int k = 0; k < KK; ++k) {
            float s = b2[k];
            for (int i = 0; i < HID; ++i) s = fmaf(h[i], w2[k * HID + i], s);
            lg[k] = s / TEMP;
            m = fmaxf(m, lg[k]);
        }
        float den = 0.f;
        for (int k = 0; k < KK; ++k) { lg[k] = expf(lg[k] - m); den += lg[k]; }
        for (int k = 0; k < KK; ++k) { a[k] = lg[k] / den; attn[b * KK + k] = a[k]; }
    }
    __syncthreads();
    if (tid < OO) {
        float s = 0.f;
        #pragma unroll
        for (int k = 0; k < KK; ++k) s = fmaf(a[k], bias_k[k * OO + tid], s);
        agg_b[b * OO + tid] = s;
    }
}

// ---------------- Stage 2b: aggregate weights -> bf16, layout wT[b][uv][o][c] ----
__global__ __launch_bounds__(256) void agg_kernel(const float* __restrict__ weight,
                                                  const float* __restrict__ attn,
                                                  u16* __restrict__ wT) {
    const int o = blockIdx.x;
    const int c = threadIdx.x;
    __shared__ float at[BB * KK];
    if (threadIdx.x < BB * KK) at[threadIdx.x] = attn[threadIdx.x];
    __syncthreads();
    float w[KK][9];
    #pragma unroll
    for (int k = 0; k < KK; ++k)
        #pragma unroll
        for (int uv = 0; uv < 9; ++uv)
            w[k][uv] = weight[(size_t)((k * OO + o) * CC + c) * 9 + uv];
    for (int b = 0; b < BB; ++b) {
        const float a0 = at[b*KK+0], a1 = at[b*KK+1], a2 = at[b*KK+2], a3 = at[b*KK+3];
        #pragma unroll
        for (int uv = 0; uv < 9; ++uv) {
            float s = a0 * w[0][uv] + a1 * w[1][uv] + a2 * w[2][uv] + a3 * w[3][uv];
            wT[(size_t)((b * 9 + uv) * OO + o) * CC + c] = f2bf(s);
        }
    }
}

// ---------------- Stage 3: MFMA implicit-GEMM conv — global_load_lds pipeline ----
// 1-D grid of 896 blocks, XCD-pinned. Block tile 128o x 224p, 4 waves (2M x 2N),
// wave 64x112 (M_rep=4, N_rep=7), K-chunks of 32 channels.
// x staged via global_load_lds into a LINEAR LDS image [q=c-group][348 slots]x16B
// (zero-padded x_t plane makes the 6x58 window contiguous + guard-free; 16B
// slot stride = conflict-free banks). The 6 stage issues for chunk cb+1 are
// spread across phases uv=0..5 of chunk cb and consumed a full chunk later, so
// the __syncthreads drain is nearly free. No ds_writes, no staging VGPRs.
// A-fragments read per-phase from L2 (compiler hoists across the barrier-free
// 9-phase chunk body). Setprio around each 28-MFMA cluster.
__global__ __launch_bounds__(256, 2) void conv_mfma(const u16* __restrict__ xt,
                                                    const u16* __restrict__ wT,
                                                    const float* __restrict__ agg_b,
                                                    float* __restrict__ out) {
    const int id   = blockIdx.x;
    const int g    = id >> 3;
    const int b    = (id & 7) + 8 * (g / 28);
    const int tile = g % 28;
    const int px   = tile % 14, oy = tile / 14;
    const int tid  = threadIdx.x;
    const int lane = tid & 63, wave = tid >> 6;
    const int wm = wave & 1, wn = wave >> 1;
    const int l15 = lane & 15, kg = lane >> 4;
    const int p0 = px * 224;

    __shared__ char xs[2][BUFB];   // 2 x 22272 B

    // stage-piece map: piece i = k*256 + tid (i < 1392); q = i/348, slot = i%348
    // LDS byte = i*16 (linear); global byte = (px*232 + slot)*64 + q*16
    uint32 soff[6]; bool sact[6];
    #pragma unroll
    for (int k = 0; k < 6; ++k) {
        const int i = k * 256 + tid;
        sact[k] = (i < 1392);
        const int q = i / NSLOT, slot = i % NSLOT;
        soff[k] = (uint32)((px * 232 + slot) * 64 + q * 16);
    }

    // B-read base byte per n-fragment: kg*QSTRIDE + S*16,
    // S = (n/56+1)*58 + n%56+1 (slot of output pixel in 6x58 window)
    int bboff[7];
    #pragma unroll
    for (int nf = 0; nf < 7; ++nf) {
        const int n = wn * 112 + nf * 16 + l15;
        const int S = (n / 56 + 1) * 58 + (n % 56 + 1);
        bboff[nf] = kg * QSTRIDE + S * 16;
    }

    // A-operand: wT[b][uv][o][c], o = oy*128 + wm*64 + mf*16 + l15, c = c0 + kg*8
    const u16* wTb = wT + (size_t)b * 9 * OO * CC
                        + (size_t)(oy * 128 + wm * 64 + l15) * CC + kg * 8;

    f32x4 acc[4][7];
    #pragma unroll
    for (int mf = 0; mf < 4; ++mf)
        #pragma unroll
        for (int nf = 0; nf < 7; ++nf)
            acc[mf][nf] = (f32x4)0.f;

    const char* xgb = (const char*)xt + (size_t)(b * 8) * PLANEB;

    // prologue: stage chunk 0 into buf0
    #pragma unroll
    for (int k = 0; k < 6; ++k)
        if (sact[k]) gload16(xgb + soff[k], &xs[0][k * 4096 + wave * 1024]);
    __syncthreads();

    for (int cb = 0; cb < 8; ++cb) {
        const char* R = xs[cb & 1];
        char* W = xs[(cb & 1) ^ 1];
        const char* xg_next = xgb + (size_t)(cb + 1) * PLANEB;
        const int c0 = cb * 32;

        #pragma unroll
        for (int uv = 0; uv < 9; ++uv) {
            // spread next-chunk staging across phases 0..5
            if (uv < 6 && cb < 7) {
                if (sact[uv]) gload16(xg_next + soff[uv], &W[uv * 4096 + wave * 1024]);
            }
            bf16x8 av[4];
            #pragma unroll
            for (int mf = 0; mf < 4; ++mf)
                av[mf] = *(const bf16x8*)(wTb + (size_t)uv * OO * CC + mf * 16 * CC + c0);
            const int dby = ((uv / 3 - 1) * 58 + (uv % 3 - 1)) * 16;
            __builtin_amdgcn_s_setprio(1);
            #pragma unroll
            for (int nf = 0; nf < 7; ++nf) {
                const bf16x8 bv = *(const bf16x8*)(R + bboff[nf] + dby);
                #pragma unroll
                for (int mf = 0; mf < 4; ++mf)
                    acc[mf][nf] = __builtin_amdgcn_mfma_f32_16x16x32_bf16(av[mf], bv, acc[mf][nf], 0, 0, 0);
            }
            __builtin_amdgcn_s_setprio(0);
        }
        __syncthreads();   // cheap: all VMEM/LDS already consumed; releases W
    }

    // epilogue: D row = kg*4 + r (-> o), col = l15 (-> p)
    const int obase = oy * 128 + wm * 64;
    float* outb = out + (size_t)b * OO * SP;
    #pragma unroll
    for (int mf = 0; mf < 4; ++mf) {
        #pragma unroll
        for (int r = 0; r < 4; ++r) {
            const int o = obase + mf * 16 + kg * 4 + r;
            const float bias = agg_b[b * OO + o];
            #pragma unroll
            for (int nf = 0; nf < 7; ++nf) {
                const int p = p0 + wn * 112 + nf * 16 + l15;
                outb[(size_t)o * SP + p] = acc[mf][nf][r] + bias;
            }
        }
    }
}

extern "C" void kernel_launch(void* const* d_in, const int* in_sizes, int n_in,
                              void* d_out, int out_size, void* d_ws, size_t ws_size,
                              hipStream_t stream) {
    const float* x      = (const float*)d_in[0];
    const float* weight = (const float*)d_in[1];
    const float* bias_k = (const float*)d_in[2];
    const float* w1     = (const float*)d_in[3];
    const float* w2     = (const float*)d_in[4];
    const float* b2     = (const float*)d_in[5];
    float* out = (float*)d_out;

    // workspace: x_t padded bf16 (55.1 MB) | wT bf16 (37.75 MB) | fp32 scratch
    u16* x_t = (u16*)d_ws;
    u16* wT  = x_t + (size_t)BB * 8 * PLANE;
    float* ws_f   = (float*)(wT + (size_t)BB * 9 * OO * CC);
    float* pooled = ws_f;
    float* attn   = ws_f + BB * 2 * CC;
    float* agg_b  = attn + BB * KK;

    trans_pool<<<dim3(8, BB), 256, 0, stream>>>(x, x_t, pooled);
    attn_kernel<<<BB, 256, 0, stream>>>(pooled, w1, w2, b2, bias_k, attn, agg_b);
    agg_kernel<<<OO, 256, 0, stream>>>(weight, attn, wT);
    conv_mfma<<<896, 256, 0, stream>>>(x_t, wT, agg_b, out);
}